// Round 4
// baseline (357.437 us; speedup 1.0000x reference)
//
#include <hip/hip_runtime.h>
#include <hip/hip_bf16.h>

typedef __attribute__((ext_vector_type(8))) short short8;
typedef __attribute__((ext_vector_type(4))) float f32x4;

#define EPS 1e-6f
#define NBLK 1024

static __device__ __forceinline__ short f2bf(float f) {
    unsigned u = __float_as_uint(f);
    unsigned r = (u + 0x7FFFu + ((u >> 16) & 1u)) >> 16;
    return (short)(unsigned short)r;
}

// ---- prep: bf16 relation embeds (padded to 64 rows) + per-relation const ----
__global__ void prep_kernel(const float* __restrict__ re, short* __restrict__ re_bf,
                            float* __restrict__ re_c2, int R) {
    int tid = threadIdx.x;          // 256 threads, 1 block
    int r = tid >> 2, q = tid & 3;  // r in 0..63, q = quarter of the row
    float v[32];
    if (r < R) {
        const float* p = re + (size_t)r * 128 + q * 32;
#pragma unroll
        for (int j = 0; j < 32; ++j) v[j] = p[j];
    } else {
#pragma unroll
        for (int j = 0; j < 32; ++j) v[j] = 0.f;
    }
    float ssq = 0.f, sum = 0.f;
#pragma unroll
    for (int j = 0; j < 32; ++j) { ssq = fmaf(v[j], v[j], ssq); sum += v[j]; }
    ssq += __shfl_xor(ssq, 1); ssq += __shfl_xor(ssq, 2);
    sum += __shfl_xor(sum, 1); sum += __shfl_xor(sum, 2);
    short* o = re_bf + r * 128 + q * 32;
#pragma unroll
    for (int j = 0; j < 32; ++j) o[j] = f2bf(v[j]);
    if (q == 0) re_c2[r] = (r < R) ? (ssq - 2.f * EPS * sum) : -1e30f;
}

// ---- main: 16-row tiles/wave; raw-x MFMA, cheap bf16 pack, x-prefetch ----
__global__ __launch_bounds__(256, 4) void loss_main(
    const float* __restrict__ mo, const float* __restrict__ tg,
    const short* __restrict__ re_bf, const float* __restrict__ re_c2,
    float* __restrict__ partials, int nrows) {
    const int tid = threadIdx.x;
    const int lane = tid & 63;
    const int widx = tid >> 6;
    const int col16 = lane & 15;   // mo-row within tile / C col
    const int kg = lane >> 4;      // k-group 0..3
    const int ko = kg * 8;

    // Relation A-fragments in LDS, shared by all 4 waves (16B/lane, conflict-free).
    __shared__ short8 bf_lds[16][64];
    if (widx == 0) {
#pragma unroll
        for (int rt = 0; rt < 4; ++rt)
#pragma unroll
            for (int s = 0; s < 4; ++s)
                bf_lds[rt * 4 + s][lane] = *reinterpret_cast<const short8*>(
                    re_bf + (rt * 16 + col16) * 128 + s * 32 + ko);
    }
    // per-lane relation constants: relation = rt*16 + kg*4 + reg  (C row ids)
    float rc[4][4];
#pragma unroll
    for (int rt = 0; rt < 4; ++rt)
#pragma unroll
        for (int reg = 0; reg < 4; ++reg)
            rc[rt][reg] = re_c2[rt * 16 + kg * 4 + reg];
    __syncthreads();

    float corr_acc = 0.f, inc_acc = 0.f;
    const int NT = nrows >> 4;       // 16-row tiles
    const int nw = gridDim.x * 4;
    int t = blockIdx.x * 4 + widx;

    if (t < NT) {
        alignas(16) float x[32];

        // prologue: load x(t0) raw
        {
            const float* rp = mo + ((size_t)(t * 16 + col16) * 128 + ko);
#pragma unroll
            for (int s = 0; s < 4; ++s) {
                *(f32x4*)(x + s * 8)     = *(const f32x4*)(rp + s * 32);
                *(f32x4*)(x + s * 8 + 4) = *(const f32x4*)(rp + s * 32 + 4);
            }
        }

        while (t < NT) {
            // issue target loads for this tile
            alignas(16) float tv[32];
            {
                const float* tp = tg + ((size_t)(t * 16 + col16) * 128 + ko);
#pragma unroll
                for (int s = 0; s < 4; ++s) {
                    *(f32x4*)(tv + s * 8)     = *(const f32x4*)(tp + s * 32);
                    *(f32x4*)(tv + s * 8 + 4) = *(const f32x4*)(tp + s * 32 + 4);
                }
            }

            // pack RAW x to bf16 fragments (no rnorm dependency; hides tv latency)
            short8 afrag[4];
#pragma unroll
            for (int s = 0; s < 4; ++s)
#pragma unroll
                for (int j = 0; j < 8; ++j)
                    afrag[s][j] = __builtin_bit_cast(short, __float2bfloat16(x[s * 8 + j]));

            // mo row stats
            float ssq = 0.f, sum = 0.f;
#pragma unroll
            for (int j = 0; j < 32; ++j) { ssq = fmaf(x[j], x[j], ssq); sum += x[j]; }
            // target-coupled stats
            float xt = 0.f, tsq = 0.f, tsum = 0.f;
#pragma unroll
            for (int j = 0; j < 32; ++j) {
                xt  = fmaf(x[j], tv[j], xt);
                tsq = fmaf(tv[j], tv[j], tsq);
                tsum += tv[j];
            }

            // prefetch next tile's mo into x (x_cur fully consumed above)
            int t2 = t + nw;
            if (t2 < NT) {
                const float* rp = mo + ((size_t)(t2 * 16 + col16) * 128 + ko);
#pragma unroll
                for (int s = 0; s < 4; ++s) {
                    *(f32x4*)(x + s * 8)     = *(const f32x4*)(rp + s * 32);
                    *(f32x4*)(x + s * 8 + 4) = *(const f32x4*)(rp + s * 32 + 4);
                }
            }

            // reduce the 5 stats across the 4 k-group lanes of this row
            ssq  += __shfl_xor(ssq, 16);  ssq  += __shfl_xor(ssq, 32);
            sum  += __shfl_xor(sum, 16);  sum  += __shfl_xor(sum, 32);
            xt   += __shfl_xor(xt, 16);   xt   += __shfl_xor(xt, 32);
            tsq  += __shfl_xor(tsq, 16);  tsq  += __shfl_xor(tsq, 32);
            tsum += __shfl_xor(tsum, 16); tsum += __shfl_xor(tsum, 32);

            float rnorm  = 1.0f / fmaxf(sqrtf(ssq), 1e-12f);
            float mo_sq  = ssq * rnorm * rnorm;
            float mo_sum = sum * rnorm;
            float mconst = fmaf(2.f * EPS, mo_sum, mo_sq) + 128.f * EPS * EPS;

            // correct term via expansion: ||rnorm*x - t + eps||^2 (kg-uniform)
            float cs = mconst + tsq - 2.f * EPS * tsum - 2.f * rnorm * xt;
            corr_acc += sqrtf(fmaxf(cs, 0.f));   // counted 4x/row, scaled 0.25 later

            // MFMA: A = relations (LDS), B = raw mo; dist^2 uses rnorm*acc
            float vmax = -1e30f;
#pragma unroll
            for (int rt = 0; rt < 4; ++rt) {
                f32x4 acc = {0.f, 0.f, 0.f, 0.f};
#pragma unroll
                for (int s = 0; s < 4; ++s)
                    acc = __builtin_amdgcn_mfma_f32_16x16x32_bf16(
                        bf_lds[rt * 4 + s][lane], afrag[s], acc, 0, 0, 0);
#pragma unroll
                for (int reg = 0; reg < 4; ++reg) {
                    float d2 = fmaf(-2.f * rnorm, acc[reg], mconst + rc[rt][reg]);
                    vmax = fmaxf(vmax, d2);
                }
            }
            vmax = fmaxf(vmax, __shfl_xor(vmax, 16));
            vmax = fmaxf(vmax, __shfl_xor(vmax, 32));
            inc_acc += sqrtf(fmaxf(vmax, 0.f));  // counted 4x/row, scaled 0.25 later

            t = t2;
        }
    }

    __shared__ float redc[256];
    __shared__ float redi[256];
    redc[tid] = corr_acc; redi[tid] = inc_acc;
    __syncthreads();
    for (int s = 128; s > 0; s >>= 1) {
        if (tid < s) { redc[tid] += redc[tid + s]; redi[tid] += redi[tid + s]; }
        __syncthreads();
    }
    if (tid == 0) {
        partials[blockIdx.x * 2]     = 0.25f * redc[0];
        partials[blockIdx.x * 2 + 1] = 0.25f * redi[0];
    }
}

// ---- final: reduce block partials to the scalar loss ----
__global__ void final_kernel(const float* __restrict__ partials, float* __restrict__ out, int nb) {
    __shared__ float rc_[256];
    __shared__ float ri_[256];
    int tid = threadIdx.x;
    float c = 0.f, ic = 0.f;
    for (int i = tid; i < nb; i += 256) { c += partials[2 * i]; ic += partials[2 * i + 1]; }
    rc_[tid] = c; ri_[tid] = ic;
    __syncthreads();
    for (int s = 128; s > 0; s >>= 1) {
        if (tid < s) { rc_[tid] += rc_[tid + s]; ri_[tid] += ri_[tid + s]; }
        __syncthreads();
    }
    if (tid == 0) out[0] = rc_[0] + 1e-4f * (1.f - ri_[0]);
}

extern "C" void kernel_launch(void* const* d_in, const int* in_sizes, int n_in,
                              void* d_out, int out_size, void* d_ws, size_t ws_size,
                              hipStream_t stream) {
    const float* mo = (const float*)d_in[0];
    const float* tg = (const float*)d_in[1];
    const float* re = (const float*)d_in[2];
    const int D = 128;
    const int nrows = in_sizes[0] / D;
    const int R = in_sizes[2] / D;

    char* ws = (char*)d_ws;
    short* re_bf    = (short*)ws;            // 64*128*2 = 16384 B
    float* re_c2    = (float*)(ws + 16384);  // 64*4 = 256 B
    float* partials = (float*)(ws + 16896);  // NBLK*2*4 = 8192 B

    prep_kernel<<<1, 256, 0, stream>>>(re, re_bf, re_c2, R);
    loss_main<<<NBLK, 256, 0, stream>>>(mo, tg, re_bf, re_c2, partials, nrows);
    final_kernel<<<1, 256, 0, stream>>>(partials, (float*)d_out, NBLK);
}

// Round 5
// 184.881 us; speedup vs baseline: 1.9333x; 1.9333x over previous
//
#include <hip/hip_runtime.h>
#include <hip/hip_bf16.h>

typedef __attribute__((ext_vector_type(8))) short short8;
typedef __attribute__((ext_vector_type(4))) float f32x4;

#define EPS 1e-6f
#define NBLK 2048

static __device__ __forceinline__ short f2bf(float f) {
    unsigned u = __float_as_uint(f);
    unsigned r = (u + 0x7FFFu + ((u >> 16) & 1u)) >> 16;
    return (short)(unsigned short)r;
}

// ---- prep: bf16 relation embeds (padded to 64 rows) + per-relation const ----
__global__ void prep_kernel(const float* __restrict__ re, short* __restrict__ re_bf,
                            float* __restrict__ re_c2, int R) {
    int tid = threadIdx.x;          // 256 threads, 1 block
    int r = tid >> 2, q = tid & 3;  // r in 0..63, q = quarter of the row
    float v[32];
    if (r < R) {
        const float* p = re + (size_t)r * 128 + q * 32;
#pragma unroll
        for (int j = 0; j < 32; ++j) v[j] = p[j];
    } else {
#pragma unroll
        for (int j = 0; j < 32; ++j) v[j] = 0.f;
    }
    float ssq = 0.f, sum = 0.f;
#pragma unroll
    for (int j = 0; j < 32; ++j) { ssq = fmaf(v[j], v[j], ssq); sum += v[j]; }
    ssq += __shfl_xor(ssq, 1); ssq += __shfl_xor(ssq, 2);
    sum += __shfl_xor(sum, 1); sum += __shfl_xor(sum, 2);
    short* o = re_bf + r * 128 + q * 32;
#pragma unroll
    for (int j = 0; j < 32; ++j) o[j] = f2bf(v[j]);
    if (q == 0) re_c2[r] = (r < R) ? (ssq - 2.f * EPS * sum) : -1e30f;
}

// ---- main: 16-row tiles/wave; raw-x MFMA, cheap bf16 pack, x-prefetch ----
__global__ __launch_bounds__(256) void loss_main(
    const float* __restrict__ mo, const float* __restrict__ tg,
    const short* __restrict__ re_bf, const float* __restrict__ re_c2,
    float* __restrict__ partials, int nrows) {
    const int tid = threadIdx.x;
    const int lane = tid & 63;
    const int widx = tid >> 6;
    const int col16 = lane & 15;   // mo-row within tile / C col
    const int kg = lane >> 4;      // k-group 0..3
    const int ko = kg * 8;

    // Relation A-fragments in LDS, shared by all 4 waves (16B/lane, conflict-free).
    __shared__ short8 bf_lds[16][64];
    if (widx == 0) {
#pragma unroll
        for (int rt = 0; rt < 4; ++rt)
#pragma unroll
            for (int s = 0; s < 4; ++s)
                bf_lds[rt * 4 + s][lane] = *reinterpret_cast<const short8*>(
                    re_bf + (rt * 16 + col16) * 128 + s * 32 + ko);
    }
    // per-lane relation constants: relation = rt*16 + kg*4 + reg  (C row ids)
    float rc[4][4];
#pragma unroll
    for (int rt = 0; rt < 4; ++rt)
#pragma unroll
        for (int reg = 0; reg < 4; ++reg)
            rc[rt][reg] = re_c2[rt * 16 + kg * 4 + reg];
    __syncthreads();

    float corr_acc = 0.f, inc_acc = 0.f;
    const int NT = nrows >> 4;       // 16-row tiles
    const int nw = gridDim.x * 4;
    int t = blockIdx.x * 4 + widx;

    if (t < NT) {
        alignas(16) float x[32];

        // prologue: load x(t0) raw
        {
            const float* rp = mo + ((size_t)(t * 16 + col16) * 128 + ko);
#pragma unroll
            for (int s = 0; s < 4; ++s) {
                *(f32x4*)(x + s * 8)     = *(const f32x4*)(rp + s * 32);
                *(f32x4*)(x + s * 8 + 4) = *(const f32x4*)(rp + s * 32 + 4);
            }
        }

        while (t < NT) {
            // issue target loads for this tile
            alignas(16) float tv[32];
            {
                const float* tp = tg + ((size_t)(t * 16 + col16) * 128 + ko);
#pragma unroll
                for (int s = 0; s < 4; ++s) {
                    *(f32x4*)(tv + s * 8)     = *(const f32x4*)(tp + s * 32);
                    *(f32x4*)(tv + s * 8 + 4) = *(const f32x4*)(tp + s * 32 + 4);
                }
            }

            // pack RAW x to bf16 fragments (no rnorm dependency; hides tv latency)
            short8 afrag[4];
#pragma unroll
            for (int s = 0; s < 4; ++s)
#pragma unroll
                for (int j = 0; j < 8; ++j)
                    afrag[s][j] = __builtin_bit_cast(short, __float2bfloat16(x[s * 8 + j]));

            // mo row stats
            float ssq = 0.f, sum = 0.f;
#pragma unroll
            for (int j = 0; j < 32; ++j) { ssq = fmaf(x[j], x[j], ssq); sum += x[j]; }
            // target-coupled stats
            float xt = 0.f, tsq = 0.f, tsum = 0.f;
#pragma unroll
            for (int j = 0; j < 32; ++j) {
                xt  = fmaf(x[j], tv[j], xt);
                tsq = fmaf(tv[j], tv[j], tsq);
                tsum += tv[j];
            }

            // prefetch next tile's mo into x (x_cur fully consumed above)
            int t2 = t + nw;
            if (t2 < NT) {
                const float* rp = mo + ((size_t)(t2 * 16 + col16) * 128 + ko);
#pragma unroll
                for (int s = 0; s < 4; ++s) {
                    *(f32x4*)(x + s * 8)     = *(const f32x4*)(rp + s * 32);
                    *(f32x4*)(x + s * 8 + 4) = *(const f32x4*)(rp + s * 32 + 4);
                }
            }

            // reduce the 5 stats across the 4 k-group lanes of this row
            ssq  += __shfl_xor(ssq, 16);  ssq  += __shfl_xor(ssq, 32);
            sum  += __shfl_xor(sum, 16);  sum  += __shfl_xor(sum, 32);
            xt   += __shfl_xor(xt, 16);   xt   += __shfl_xor(xt, 32);
            tsq  += __shfl_xor(tsq, 16);  tsq  += __shfl_xor(tsq, 32);
            tsum += __shfl_xor(tsum, 16); tsum += __shfl_xor(tsum, 32);

            float rnorm  = 1.0f / fmaxf(sqrtf(ssq), 1e-12f);
            float mo_sq  = ssq * rnorm * rnorm;
            float mo_sum = sum * rnorm;
            float mconst = fmaf(2.f * EPS, mo_sum, mo_sq) + 128.f * EPS * EPS;

            // correct term via expansion: ||rnorm*x - t + eps||^2 (kg-uniform)
            float cs = mconst + tsq - 2.f * EPS * tsum - 2.f * rnorm * xt;
            corr_acc += sqrtf(fmaxf(cs, 0.f));   // counted 4x/row, scaled 0.25 later

            // MFMA: A = relations (LDS), B = raw mo; dist^2 uses rnorm*acc
            float vmax = -1e30f;
#pragma unroll
            for (int rt = 0; rt < 4; ++rt) {
                f32x4 acc = {0.f, 0.f, 0.f, 0.f};
#pragma unroll
                for (int s = 0; s < 4; ++s)
                    acc = __builtin_amdgcn_mfma_f32_16x16x32_bf16(
                        bf_lds[rt * 4 + s][lane], afrag[s], acc, 0, 0, 0);
#pragma unroll
                for (int reg = 0; reg < 4; ++reg) {
                    float d2 = fmaf(-2.f * rnorm, acc[reg], mconst + rc[rt][reg]);
                    vmax = fmaxf(vmax, d2);
                }
            }
            vmax = fmaxf(vmax, __shfl_xor(vmax, 16));
            vmax = fmaxf(vmax, __shfl_xor(vmax, 32));
            inc_acc += sqrtf(fmaxf(vmax, 0.f));  // counted 4x/row, scaled 0.25 later

            t = t2;
        }
    }

    __shared__ float redc[256];
    __shared__ float redi[256];
    redc[tid] = corr_acc; redi[tid] = inc_acc;
    __syncthreads();
    for (int s = 128; s > 0; s >>= 1) {
        if (tid < s) { redc[tid] += redc[tid + s]; redi[tid] += redi[tid + s]; }
        __syncthreads();
    }
    if (tid == 0) {
        partials[blockIdx.x * 2]     = 0.25f * redc[0];
        partials[blockIdx.x * 2 + 1] = 0.25f * redi[0];
    }
}

// ---- final: reduce block partials to the scalar loss ----
__global__ void final_kernel(const float* __restrict__ partials, float* __restrict__ out, int nb) {
    __shared__ float rc_[256];
    __shared__ float ri_[256];
    int tid = threadIdx.x;
    float c = 0.f, ic = 0.f;
    for (int i = tid; i < nb; i += 256) { c += partials[2 * i]; ic += partials[2 * i + 1]; }
    rc_[tid] = c; ri_[tid] = ic;
    __syncthreads();
    for (int s = 128; s > 0; s >>= 1) {
        if (tid < s) { rc_[tid] += rc_[tid + s]; ri_[tid] += ri_[tid + s]; }
        __syncthreads();
    }
    if (tid == 0) out[0] = rc_[0] + 1e-4f * (1.f - ri_[0]);
}

extern "C" void kernel_launch(void* const* d_in, const int* in_sizes, int n_in,
                              void* d_out, int out_size, void* d_ws, size_t ws_size,
                              hipStream_t stream) {
    const float* mo = (const float*)d_in[0];
    const float* tg = (const float*)d_in[1];
    const float* re = (const float*)d_in[2];
    const int D = 128;
    const int nrows = in_sizes[0] / D;
    const int R = in_sizes[2] / D;

    char* ws = (char*)d_ws;
    short* re_bf    = (short*)ws;            // 64*128*2 = 16384 B
    float* re_c2    = (float*)(ws + 16384);  // 64*4 = 256 B
    float* partials = (float*)(ws + 16896);  // NBLK*2*4 = 16384 B

    prep_kernel<<<1, 256, 0, stream>>>(re, re_bf, re_c2, R);
    loss_main<<<NBLK, 256, 0, stream>>>(mo, tg, re_bf, re_c2, partials, nrows);
    final_kernel<<<1, 256, 0, stream>>>(partials, (float*)d_out, NBLK);
}